// Round 1
// baseline (94.140 us; speedup 1.0000x reference)
//
#include <hip/hip_runtime.h>
#include <math.h>

#define BB 2
#define LL 2048
#define HH 128
#define NN 64
#define CH 64
#define NCH 32          /* LL/CH */
#define EPSF 1e-12f
#define T_A 13.8f       /* |z| > e^-13.8 = 1e-6  -> gate == 1 to <1e-6 */
#define T_C 48.3f       /* |z| < e^-48.3         -> |gate| < 1.1e-9, drop input */

// Full 64-lane f32 sum via DPP (result valid in lane 63). VALU-only.
__device__ __forceinline__ float wave_sum64(float x) {
  float t;
  t = __int_as_float(__builtin_amdgcn_update_dpp(0, __float_as_int(x), 0x111, 0xf, 0xf, true)); x += t; // row_shr:1
  t = __int_as_float(__builtin_amdgcn_update_dpp(0, __float_as_int(x), 0x112, 0xf, 0xf, true)); x += t; // row_shr:2
  t = __int_as_float(__builtin_amdgcn_update_dpp(0, __float_as_int(x), 0x114, 0xf, 0xf, true)); x += t; // row_shr:4
  t = __int_as_float(__builtin_amdgcn_update_dpp(0, __float_as_int(x), 0x118, 0xf, 0xf, true)); x += t; // row_shr:8
  t = __int_as_float(__builtin_amdgcn_update_dpp(0, __float_as_int(x), 0x142, 0xa, 0xf, true)); x += t; // row_bcast:15
  t = __int_as_float(__builtin_amdgcn_update_dpp(0, __float_as_int(x), 0x143, 0xc, 0xf, true)); x += t; // row_bcast:31
  return x;
}

// Per-lane (h, n=lane) derived parameters. k = Cc * dB (C folded into state).
__device__ __forceinline__ void lane_params(
    const float* lar, const float* aim, const float* Bp, const float* ldt, const float* Cp,
    int h, int n,
    float& ar, float& ai, float& are, float& aie, float& kr, float& ki)
{
  float dt  = expf(ldt[0]);
  float lre = -expf(lar[h*NN + n]);   // Lam.re
  float w   = aim[h*NN + n];          // Lam.im
  ar = lre * dt;                      // dA.re
  ai = w   * dt;                      // dA.im
  float er = expf(ar);
  float s, c;
  sincosf(ai, &s, &c);
  are = er * c;  aie = er * s;        // a = exp(dA)
  float em1r = are - 1.0f, em1i = aie;
  float il2  = 1.0f / (lre*lre + w*w);
  float qr = (em1r*lre + em1i*w) * il2;   // (e^dA - 1)/Lam
  float qi = (em1i*lre - em1r*w) * il2;
  float br = Bp[(h*NN+n)*2+0], bi = Bp[(h*NN+n)*2+1];
  float dbr = br*qr - bi*qi, dbi = br*qi + bi*qr;
  float cr = Cp[n*2+0], ci = Cp[n*2+1];
  kr = cr*dbr - ci*dbi;
  ki = cr*dbi + ci*dbr;
}

// Uniform regime split points from wave min/max of decay rate.
__device__ __forceinline__ void regime_limits(float ar, int& tA_lim, int& tC_lim) {
  float arn = -ar;
  float mx = arn, mn = arn;
  #pragma unroll
  for (int m = 32; m >= 1; m >>= 1) {
    mx = fmaxf(mx, __shfl_xor(mx, m));
    mn = fminf(mn, __shfl_xor(mn, m));
  }
  tA_lim = (int)(T_A / mx);        // t <= tA_lim : all lanes gate==1
  tC_lim = (int)(T_C / mn) + 1;    // t >= tC_lim : all lanes input negligible
}

extern "C" __global__ __launch_bounds__(256, 4)
void s4d_k1(const float* __restrict__ u, const float* __restrict__ lar,
            const float* __restrict__ aim, const float* __restrict__ Bp,
            const float* __restrict__ ldt, const float* __restrict__ Cp,
            float2* __restrict__ states)
{
  int lane = threadIdx.x & 63;
  int wid  = blockIdx.x * 4 + (threadIdx.x >> 6);
  int c = wid & (NCH-1);
  int h = (wid >> 5) & (HH-1);
  int b = wid >> 12;

  float ar, ai, are, aie, kr, ki;
  lane_params(lar, aim, Bp, ldt, Cp, h, lane, ar, ai, are, aie, kr, ki);
  int tA_lim, tC_lim;
  regime_limits(ar, tA_lim, tC_lim);

  int t0 = c * CH, t1 = t0 + CH;
  int e1 = min(t1, max(t0, tA_lim + 1));
  int e2 = min(t1, max(e1, tC_lim));

  const float* ub = u + (size_t)b * LL * HH + h;
  float pr = 0.f, pi = 0.f;

  for (int t = t0; t < e1; ++t) {            // regime A: gate == 1
    float uv = ub[t * HH];
    float prn = fmaf(are, pr, fmaf(-aie, pi, uv * kr));
    float pin = fmaf(aie, pr, fmaf( are, pi, uv * ki));
    pr = prn; pi = pin;
  }
  if (e2 > e1) {                             // regime B: full gate
    float rho = expf(ar * (float)e1);
    float th  = ai * (float)e1;
    float s, cth; sincosf(th, &s, &cth);
    float zr = rho * cth, zi = rho * s;
    for (int t = e1; t < e2; ++t) {
      float uv  = ub[t * HH];
      float dr  = zr + EPSF;
      float den = fmaf(dr, dr, zi*zi);
      float inv = 1.0f / den;
      float gr  = fmaf(zr, dr, zi*zi) * inv;
      float gi  = (zi*dr - zr*zi) * inv;
      float kgr = kr*gr - ki*gi, kgi = kr*gi + ki*gr;
      float prn = fmaf(are, pr, fmaf(-aie, pi, uv * kgr));
      float pin = fmaf(aie, pr, fmaf( are, pi, uv * kgi));
      pr = prn; pi = pin;
      float zrn = zr*are - zi*aie, zin = zr*aie + zi*are;
      zr = zrn; zi = zin;
    }
  }
  int dC = t1 - e2;                          // regime C: input == 0, pure decay
  if (dC > 0) {
    float rr = expf(ar * (float)dC);
    float s, cth; sincosf(ai * (float)dC, &s, &cth);
    float wr2 = rr * cth, wi2 = rr * s;
    float prn = pr*wr2 - pi*wi2;
    float pin = pr*wi2 + pi*wr2;
    pr = prn; pi = pin;
  }
  states[(((size_t)b*HH + h)*NCH + c)*NN + lane] = make_float2(pr, pi);
}

extern "C" __global__ __launch_bounds__(256)
void s4d_k2(const float* __restrict__ lar, const float* __restrict__ aim,
            const float* __restrict__ ldt, float2* __restrict__ states)
{
  int tid = blockIdx.x * 256 + threadIdx.x;   // 0..16383 = (b,h,n)
  int n = tid & 63;
  int h = (tid >> 6) & (HH-1);
  int b = tid >> 13;
  float dt  = expf(ldt[0]);
  float lre = -expf(lar[h*NN+n]);
  float ar  = lre*dt, ai = aim[h*NN+n]*dt;
  float rr  = expf(ar * 64.f);
  float s, c; sincosf(ai * 64.f, &s, &c);
  float Ar = rr*c, Ai = rr*s;                 // A64 = exp(dA*64)
  float xr = 0.f, xi = 0.f;
  size_t base = ((size_t)b*HH + h)*NCH*NN + n;
  for (int cc = 0; cc < NCH; ++cc) {
    size_t idx = base + (size_t)cc*NN;
    float2 tmp = states[idx];
    states[idx] = make_float2(xr, xi);        // exclusive carry, in-place
    float xrn = fmaf(Ar, xr, fmaf(-Ai, xi, tmp.x));
    float xin = fmaf(Ai, xr, fmaf( Ar, xi, tmp.y));
    xr = xrn; xi = xin;
  }
}

extern "C" __global__ __launch_bounds__(256, 4)
void s4d_k3(const float* __restrict__ u, const float* __restrict__ lar,
            const float* __restrict__ aim, const float* __restrict__ Bp,
            const float* __restrict__ ldt, const float* __restrict__ Cp,
            const float* __restrict__ Dp,
            const float2* __restrict__ states, float* __restrict__ out)
{
  int lane = threadIdx.x & 63;
  int wid  = blockIdx.x * 4 + (threadIdx.x >> 6);
  int c = wid & (NCH-1);
  int h = (wid >> 5) & (HH-1);
  int b = wid >> 12;

  float ar, ai, are, aie, kr, ki;
  lane_params(lar, aim, Bp, ldt, Cp, h, lane, ar, ai, are, aie, kr, ki);
  int tA_lim, tC_lim;
  regime_limits(ar, tA_lim, tC_lim);

  int t0 = c * CH, t1 = t0 + CH;
  int e1 = min(t1, max(t0, tA_lim + 1));
  int e2 = min(t1, max(e1, tC_lim));

  const float* ub = u + (size_t)b * LL * HH + h;
  float2 cin = states[(((size_t)b*HH + h)*NCH + c)*NN + lane];
  float pr = cin.x, pi = cin.y;
  float ybuf = 0.f;

  for (int t = t0; t < e1; ++t) {
    float uv = ub[t * HH];
    float prn = fmaf(are, pr, fmaf(-aie, pi, uv * kr));
    float pin = fmaf(aie, pr, fmaf( are, pi, uv * ki));
    pr = prn; pi = pin;
    float ys = wave_sum64(pr);
    float yb = __int_as_float(__builtin_amdgcn_readlane(__float_as_int(ys), 63));
    if (lane == (t - t0)) ybuf = yb;
  }
  if (e2 > e1) {
    float rho = expf(ar * (float)e1);
    float th  = ai * (float)e1;
    float s, cth; sincosf(th, &s, &cth);
    float zr = rho * cth, zi = rho * s;
    for (int t = e1; t < e2; ++t) {
      float uv  = ub[t * HH];
      float dr  = zr + EPSF;
      float den = fmaf(dr, dr, zi*zi);
      float inv = 1.0f / den;
      float gr  = fmaf(zr, dr, zi*zi) * inv;
      float gi  = (zi*dr - zr*zi) * inv;
      float kgr = kr*gr - ki*gi, kgi = kr*gi + ki*gr;
      float prn = fmaf(are, pr, fmaf(-aie, pi, uv * kgr));
      float pin = fmaf(aie, pr, fmaf( are, pi, uv * kgi));
      pr = prn; pi = pin;
      float zrn = zr*are - zi*aie, zin = zr*aie + zi*are;
      zr = zrn; zi = zin;
      float ys = wave_sum64(pr);
      float yb = __int_as_float(__builtin_amdgcn_readlane(__float_as_int(ys), 63));
      if (lane == (t - t0)) ybuf = yb;
    }
  }
  for (int t = e2; t < t1; ++t) {            // regime C: pure decay, still emit y
    float prn = fmaf(are, pr, -aie*pi);
    float pin = fmaf(aie, pr,  are*pi);
    pr = prn; pi = pin;
    float ys = wave_sum64(pr);
    float yb = __int_as_float(__builtin_amdgcn_readlane(__float_as_int(ys), 63));
    if (lane == (t - t0)) ybuf = yb;
  }

  int tl = t0 + lane;
  float uvl = ub[tl * HH];
  out[(size_t)b*LL*HH + (size_t)tl*HH + h] = ybuf + uvl * Dp[h];
}

extern "C" void kernel_launch(void* const* d_in, const int* in_sizes, int n_in,
                              void* d_out, int out_size, void* d_ws, size_t ws_size,
                              hipStream_t stream)
{
  const float* u   = (const float*)d_in[0];
  const float* lar = (const float*)d_in[1];
  const float* aim = (const float*)d_in[2];
  const float* Bp  = (const float*)d_in[3];
  const float* ldt = (const float*)d_in[4];
  const float* Cp  = (const float*)d_in[5];
  const float* Dp  = (const float*)d_in[6];
  float* out = (float*)d_out;
  float2* states = (float2*)d_ws;   // B*H*NCH*N complex = 4 MB

  dim3 blk(256);
  s4d_k1<<<dim3(BB*HH*NCH/4), blk, 0, stream>>>(u, lar, aim, Bp, ldt, Cp, states);
  s4d_k2<<<dim3(BB*HH*NN/256), blk, 0, stream>>>(lar, aim, ldt, states);
  s4d_k3<<<dim3(BB*HH*NCH/4), blk, 0, stream>>>(u, lar, aim, Bp, ldt, Cp, Dp, states, out);
}

// Round 2
// 86.765 us; speedup vs baseline: 1.0850x; 1.0850x over previous
//
#include <hip/hip_runtime.h>
#include <math.h>

#define BB 2
#define LL 2048
#define HH 128
#define NN 64
#define CH 64
#define NCH 32          /* LL/CH */
#define EPSF 1e-12f
#define T_A 13.8f       /* |z| > e^-13.8 = 1e-6  -> gate == 1 to <1e-6 */
#define T_C 48.3f       /* |z| < e^-48.3         -> |gate| < 1.1e-9, drop input */

// 4-step butterfly within each 16-lane row; ALL 16 lanes end with the row sum.
__device__ __forceinline__ float row_sum16(float x) {
  float t;
  t = __int_as_float(__builtin_amdgcn_update_dpp(0, __float_as_int(x), 0xB1,  0xf, 0xf, true)); x += t; // quad_perm [1,0,3,2] (xor1)
  t = __int_as_float(__builtin_amdgcn_update_dpp(0, __float_as_int(x), 0x4E,  0xf, 0xf, true)); x += t; // quad_perm [2,3,0,1] (xor2)
  t = __int_as_float(__builtin_amdgcn_update_dpp(0, __float_as_int(x), 0x141, 0xf, 0xf, true)); x += t; // row_half_mirror (xor4 after quads uniform)
  t = __int_as_float(__builtin_amdgcn_update_dpp(0, __float_as_int(x), 0x140, 0xf, 0xf, true)); x += t; // row_mirror (xor8 after halves uniform)
  return x;
}

__device__ __forceinline__ float bcast_lane(float v, int idx) {
  return __int_as_float(__builtin_amdgcn_readlane(__float_as_int(v), idx));
}

// Per-lane (h, n=lane) derived parameters. k = Cc * dB (C folded into state).
__device__ __forceinline__ void lane_params(
    const float* lar, const float* aim, const float* Bp, const float* ldt, const float* Cp,
    int h, int n,
    float& ar, float& ai, float& are, float& aie, float& kr, float& ki)
{
  float dt  = expf(ldt[0]);
  float lre = -expf(lar[h*NN + n]);   // Lam.re
  float w   = aim[h*NN + n];          // Lam.im
  ar = lre * dt;                      // dA.re
  ai = w   * dt;                      // dA.im
  float er = expf(ar);
  float s, c;
  sincosf(ai, &s, &c);
  are = er * c;  aie = er * s;        // a = exp(dA)
  float em1r = are - 1.0f, em1i = aie;
  float il2  = 1.0f / (lre*lre + w*w);
  float qr = (em1r*lre + em1i*w) * il2;   // (e^dA - 1)/Lam
  float qi = (em1i*lre - em1r*w) * il2;
  float br = Bp[(h*NN+n)*2+0], bi = Bp[(h*NN+n)*2+1];
  float dbr = br*qr - bi*qi, dbi = br*qi + bi*qr;
  float cr = Cp[n*2+0], ci = Cp[n*2+1];
  kr = cr*dbr - ci*dbi;
  ki = cr*dbi + ci*dbr;
}

// Uniform regime split points from wave min/max of decay rate.
__device__ __forceinline__ void regime_limits(float ar, int& tA_lim, int& tC_lim) {
  float arn = -ar;
  float mx = arn, mn = arn;
  #pragma unroll
  for (int m = 32; m >= 1; m >>= 1) {
    mx = fmaxf(mx, __shfl_xor(mx, m));
    mn = fminf(mn, __shfl_xor(mn, m));
  }
  tA_lim = (int)(T_A / mx);        // t <= tA_lim : all lanes gate==1
  tC_lim = (int)(T_C / mn) + 1;    // t >= tC_lim : all lanes input negligible
}

extern "C" __global__ __launch_bounds__(256, 4)
void s4d_k1(const float* __restrict__ u, const float* __restrict__ lar,
            const float* __restrict__ aim, const float* __restrict__ Bp,
            const float* __restrict__ ldt, const float* __restrict__ Cp,
            float2* __restrict__ states)
{
  int lane = threadIdx.x & 63;
  int wid  = blockIdx.x * 4 + (threadIdx.x >> 6);
  int c = wid & (NCH-1);
  int h = (wid >> 5) & (HH-1);
  int b = wid >> 12;

  float ar, ai, are, aie, kr, ki;
  lane_params(lar, aim, Bp, ldt, Cp, h, lane, ar, ai, are, aie, kr, ki);
  int tA_lim, tC_lim;
  regime_limits(ar, tA_lim, tC_lim);

  int t0 = c * CH, t1 = t0 + CH;
  size_t sidx = (((size_t)b*HH + h)*NCH + c)*NN + lane;

  if (t0 >= tC_lim) {                        // dead tail: local state negligible
    states[sidx] = make_float2(0.f, 0.f);
    return;
  }

  int e1 = min(t1, max(t0, tA_lim + 1));
  int e2 = min(t1, max(e1, tC_lim));

  const float* ub = u + (size_t)b * LL * HH + h;
  float ureg = ub[(size_t)(t0 + lane) * HH]; // u[t0+lane] for this (b,h)
  float pr = 0.f, pi = 0.f;

  #pragma unroll 8
  for (int t = t0; t < e1; ++t) {            // regime A: gate == 1
    float uv = bcast_lane(ureg, t - t0);
    float prn = fmaf(are, pr, fmaf(-aie, pi, uv * kr));
    float pin = fmaf(aie, pr, fmaf( are, pi, uv * ki));
    pr = prn; pi = pin;
  }
  if (e2 > e1) {                             // regime B: full gate
    float rho = expf(ar * (float)e1);
    float th  = ai * (float)e1;
    float s, cth; sincosf(th, &s, &cth);
    float zr = rho * cth, zi = rho * s;
    for (int t = e1; t < e2; ++t) {
      float uv  = bcast_lane(ureg, t - t0);
      float dr  = zr + EPSF;
      float den = fmaf(dr, dr, zi*zi);
      float inv = 1.0f / den;
      float gr  = fmaf(zr, dr, zi*zi) * inv;
      float gi  = (zi*dr - zr*zi) * inv;
      float kgr = kr*gr - ki*gi, kgi = kr*gi + ki*gr;
      float prn = fmaf(are, pr, fmaf(-aie, pi, uv * kgr));
      float pin = fmaf(aie, pr, fmaf( are, pi, uv * kgi));
      pr = prn; pi = pin;
      float zrn = zr*are - zi*aie, zin = zr*aie + zi*are;
      zr = zrn; zi = zin;
    }
  }
  int dC = t1 - e2;                          // regime C: input == 0, pure decay
  if (dC > 0) {
    float rr = expf(ar * (float)dC);
    float s, cth; sincosf(ai * (float)dC, &s, &cth);
    float wr2 = rr * cth, wi2 = rr * s;
    float prn = pr*wr2 - pi*wi2;
    float pin = pr*wi2 + pi*wr2;
    pr = prn; pi = pin;
  }
  states[sidx] = make_float2(pr, pi);
}

extern "C" __global__ __launch_bounds__(64)
void s4d_k2(const float* __restrict__ lar, const float* __restrict__ aim,
            const float* __restrict__ ldt, float2* __restrict__ states)
{
  int tid = blockIdx.x * 64 + threadIdx.x;    // 0..16383 = (b,h,n)
  int n = tid & 63;
  int h = (tid >> 6) & (HH-1);
  int b = tid >> 13;
  float dt  = expf(ldt[0]);
  float lre = -expf(lar[h*NN+n]);
  float ar  = lre*dt, ai = aim[h*NN+n]*dt;
  float rr  = expf(ar * 64.f);
  float s, c; sincosf(ai * 64.f, &s, &c);
  float Ar = rr*c, Ai = rr*s;                 // A64 = exp(dA*64)
  float xr = 0.f, xi = 0.f;
  size_t base = ((size_t)b*HH + h)*NCH*NN + n;
  #pragma unroll
  for (int cc = 0; cc < NCH; ++cc) {
    size_t idx = base + (size_t)cc*NN;
    float2 tmp = states[idx];
    states[idx] = make_float2(xr, xi);        // exclusive carry, in-place
    float xrn = fmaf(Ar, xr, fmaf(-Ai, xi, tmp.x));
    float xin = fmaf(Ai, xr, fmaf( Ar, xi, tmp.y));
    xr = xrn; xi = xin;
  }
}

extern "C" __global__ __launch_bounds__(256, 4)
void s4d_k3(const float* __restrict__ u, const float* __restrict__ lar,
            const float* __restrict__ aim, const float* __restrict__ Bp,
            const float* __restrict__ ldt, const float* __restrict__ Cp,
            const float* __restrict__ Dp,
            const float2* __restrict__ states, float* __restrict__ out)
{
  __shared__ float lds[4 * 256];             // 4 waves x (64 t x 4 row-partials)
  int lane = threadIdx.x & 63;
  int wv   = threadIdx.x >> 6;
  int wid  = blockIdx.x * 4 + wv;
  int c = wid & (NCH-1);
  int h = (wid >> 5) & (HH-1);
  int b = wid >> 12;
  float* myl = lds + wv * 256;
  int row = lane >> 4;

  float ar, ai, are, aie, kr, ki;
  lane_params(lar, aim, Bp, ldt, Cp, h, lane, ar, ai, are, aie, kr, ki);
  int tA_lim, tC_lim;
  regime_limits(ar, tA_lim, tC_lim);

  int t0 = c * CH, t1 = t0 + CH;
  const float* ub = u + (size_t)b * LL * HH + h;
  float ureg = ub[(size_t)(t0 + lane) * HH];
  int tl = t0 + lane;
  size_t oidx = (size_t)b*LL*HH + (size_t)tl*HH + h;
  float Dh = Dp[h];

  if (t0 >= tC_lim) {                        // dead tail: y ~ 0
    out[oidx] = ureg * Dh;
    return;
  }

  int e1 = min(t1, max(t0, tA_lim + 1));
  int e2 = min(t1, max(e1, tC_lim));

  float2 cin = states[(((size_t)b*HH + h)*NCH + c)*NN + lane];
  float pr = cin.x, pi = cin.y;
  bool wrt = (lane & 15) == 0;

  #pragma unroll 8
  for (int t = t0; t < e1; ++t) {            // regime A
    float uv = bcast_lane(ureg, t - t0);
    float prn = fmaf(are, pr, fmaf(-aie, pi, uv * kr));
    float pin = fmaf(aie, pr, fmaf( are, pi, uv * ki));
    pr = prn; pi = pin;
    float ps = row_sum16(pr);
    if (wrt) myl[((t - t0) << 2) + row] = ps;
  }
  if (e2 > e1) {                             // regime B
    float rho = expf(ar * (float)e1);
    float th  = ai * (float)e1;
    float s, cth; sincosf(th, &s, &cth);
    float zr = rho * cth, zi = rho * s;
    for (int t = e1; t < e2; ++t) {
      float uv  = bcast_lane(ureg, t - t0);
      float dr  = zr + EPSF;
      float den = fmaf(dr, dr, zi*zi);
      float inv = 1.0f / den;
      float gr  = fmaf(zr, dr, zi*zi) * inv;
      float gi  = (zi*dr - zr*zi) * inv;
      float kgr = kr*gr - ki*gi, kgi = kr*gi + ki*gr;
      float prn = fmaf(are, pr, fmaf(-aie, pi, uv * kgr));
      float pin = fmaf(aie, pr, fmaf( are, pi, uv * kgi));
      pr = prn; pi = pin;
      float zrn = zr*are - zi*aie, zin = zr*aie + zi*are;
      zr = zrn; zi = zin;
      float ps = row_sum16(pr);
      if (wrt) myl[((t - t0) << 2) + row] = ps;
    }
  }
  #pragma unroll 8
  for (int t = e2; t < t1; ++t) {            // regime C: pure decay, still emit y
    float prn = fmaf(are, pr, -aie*pi);
    float pin = fmaf(aie, pr,  are*pi);
    pr = prn; pi = pin;
    float ps = row_sum16(pr);
    if (wrt) myl[((t - t0) << 2) + row] = ps;
  }

  float4 yv = *reinterpret_cast<const float4*>(&myl[lane << 2]);
  out[oidx] = (yv.x + yv.y) + (yv.z + yv.w) + ureg * Dh;
}

extern "C" void kernel_launch(void* const* d_in, const int* in_sizes, int n_in,
                              void* d_out, int out_size, void* d_ws, size_t ws_size,
                              hipStream_t stream)
{
  const float* u   = (const float*)d_in[0];
  const float* lar = (const float*)d_in[1];
  const float* aim = (const float*)d_in[2];
  const float* Bp  = (const float*)d_in[3];
  const float* ldt = (const float*)d_in[4];
  const float* Cp  = (const float*)d_in[5];
  const float* Dp  = (const float*)d_in[6];
  float* out = (float*)d_out;
  float2* states = (float2*)d_ws;   // B*H*NCH*N complex = 4 MB

  dim3 blk(256);
  s4d_k1<<<dim3(BB*HH*NCH/4), blk, 0, stream>>>(u, lar, aim, Bp, ldt, Cp, states);
  s4d_k2<<<dim3(BB*HH*NN/64), dim3(64), 0, stream>>>(lar, aim, ldt, states);
  s4d_k3<<<dim3(BB*HH*NCH/4), blk, 0, stream>>>(u, lar, aim, Bp, ldt, Cp, Dp, states, out);
}